// Round 11
// baseline (61.748 us; speedup 1.0000x reference)
//
#include <hip/hip_runtime.h>
#include <hip/hip_bf16.h>

typedef float  f32x4  __attribute__((ext_vector_type(4)));
typedef short  short8 __attribute__((ext_vector_type(8)));

#define NMAIN 12              // main K-steps of 64 (k < 768)
#define BM    64
#define AB    8192            // A buf: [2 kk][4 kc][64 row][8] bf16
#define BBUF  16384           // B buf: 2 tiles of [4 kc][128 col][8] bf16
#define BOFFS (3 * AB)        // 24576
#define POOLB (3 * AB + 3 * BBUF)   // 73728 -> 2 blocks/CU

static __device__ __forceinline__ unsigned short f2bf(float f) {
    unsigned int u = __float_as_uint(f);
    unsigned int r = (u + 0x7fffu + ((u >> 16) & 1u)) >> 16;   // RNE
    return (unsigned short)r;
}
static __device__ __forceinline__ float bf2f(unsigned short h) {
    return __uint_as_float(((unsigned int)h) << 16);
}
static __device__ __forceinline__ uint2 pack4(f32x4 v) {
    __hip_bfloat162 p0 = __float22bfloat162_rn(make_float2(v[0], v[1]));
    __hip_bfloat162 p1 = __float22bfloat162_rn(make_float2(v[2], v[3]));
    uint2 r;
    r.x = *reinterpret_cast<unsigned int*>(&p0);
    r.y = *reinterpret_cast<unsigned int*>(&p1);
    return r;
}

// W_eff = fc1_w o ConvMatrix, layout [kt32][kc][128 col][8] bf16 (as r10);
// fc2 bf16 at ws[102400..103679].
__global__ __launch_bounds__(256) void weff_prep(
    const float* __restrict__ fc1_w,    // [128][676]
    const float* __restrict__ conv_w,   // [3][3]
    const float* __restrict__ fc2_w,    // [10][128]
    unsigned short* __restrict__ ws)
{
    int idx = blockIdx.x * 256 + threadIdx.x;   // o*800 + p
    if (idx >= 128 * 800) return;
    if (idx < 1280) ws[102400 + idx] = f2bf(fc2_w[idx]);
    int o = idx / 800, p = idx - o * 800;
    float s = 0.f;
    if (p < 784) {
        int y = p / 28, xx = p - y * 28;
        #pragma unroll
        for (int dr = 0; dr < 3; ++dr) {
            int r = y - dr;
            if (r < 0 || r > 25) continue;
            #pragma unroll
            for (int dc = 0; dc < 3; ++dc) {
                int c = xx - dc;
                if (c < 0 || c > 25) continue;
                s += fc1_w[o * 676 + r * 26 + c] * conv_w[dr * 3 + dc];
            }
        }
    }
    int kt = p >> 5, kk = p & 31;
    ws[kt * 4096 + (kk >> 3) * 1024 + o * 8 + (kk & 7)] = f2bf(s);
}

// Fused: H = relu(X @ Weff^T + b1); out = H @ fc2^T + b2
// BK=64: 12 main steps + 32-wide tail. Per thread-visit X reads 32B
// contiguous (2x DRAM run length vs BK=32), 13 barriers (was 25),
// 8 MFMA + 10 ds_read_b128 per wave per step. A reg-staged 3-deep;
// B gload_lds 3-buf, 2-step flight; steady wait vmcnt(4).
__global__ __launch_bounds__(512, 4) void fused_fwd(
    const float* __restrict__ x,              // [B][784]
    const unsigned short* __restrict__ weff,  // [25][4][128][8] bf16 (+fc2wb)
    const float* __restrict__ fc1_b,          // [128]
    const float* __restrict__ fc2_b,          // [10]
    float* __restrict__ out,                  // [B][10]
    int B)
{
    __shared__ __align__(16) char pool[POOLB];   // 72 KB; Hs overlays after

    const int tid  = threadIdx.x;
    const int lane = tid & 63;
    const int wid  = tid >> 6;                // 0..7
    const int wr   = wid >> 1;                // 0..3: 16-row band
    const int wc   = wid & 1;                 // 0..1: 64-col half
    const int r16  = lane & 15;
    const int kc   = lane >> 4;               // 0..3 (8-bf16 k-chunk)
    const int m0   = blockIdx.x * BM;
    const unsigned short* fc2wb = weff + 102400;

    // ---- A staging: thread t -> row sr, 8-f32 granule g (32B contiguous)
    const int sr = tid >> 3;                  // 0..63
    const int g  = tid & 7;                   // k-granule of 8 f32
    int grow = m0 + sr; if (grow >= B) grow = B - 1;
    const float* xr = x + (size_t)grow * 784;
    const int awb = (g >> 2) * 4096 + (g & 3) * 1024 + sr * 16;  // byte in A buf

    f32x4 av[3][2];                            // 3 sets x 2 float4

#define LD_A(s_, kt_) do {                                                    \
        int k_ = (kt_) * 64 + g * 8; if (k_ > 776) k_ = 0;                    \
        av[s_][0] = *reinterpret_cast<const f32x4*>(xr + k_);                 \
        av[s_][1] = *reinterpret_cast<const f32x4*>(xr + k_ + 4);             \
    } while (0)

#define WR_A(s_, bi_) do {                                                    \
        uint2 q0_ = pack4(av[s_][0]);                                         \
        uint2 q1_ = pack4(av[s_][1]);                                         \
        uint4 q_; q_.x = q0_.x; q_.y = q0_.y; q_.z = q1_.x; q_.w = q1_.y;     \
        *reinterpret_cast<uint4*>(pool + (bi_) * AB + awb) = q_;              \
    } while (0)

#define GL_B(bi_, tile_, h_) __builtin_amdgcn_global_load_lds(                \
        (const __attribute__((address_space(1))) void*)                      \
            (weff + (size_t)(tile_) * 4096 + tid * 8),                        \
        (__attribute__((address_space(3))) void*)                            \
            (pool + BOFFS + (bi_) * BBUF + (h_) * 8192 + tid * 16), 16, 0, 0)

    // ---- frag read offsets
    const int arow = wr * 16 + r16;
    const int aoff0 = 0    + kc * 1024 + arow * 16;            // kk=0
    const int aoff1 = 4096 + kc * 1024 + arow * 16;            // kk=1
    const int bcol = wc * 64 + r16;                            // j: +256
    const int boff0 = BOFFS + 0    + kc * 2048 + bcol * 16;    // kk=0
    const int boff1 = BOFFS + 8192 + kc * 2048 + bcol * 16;    // kk=1

    f32x4 acc[4];
    #pragma unroll
    for (int j = 0; j < 4; ++j) acc[j] = (f32x4)(0.f);

    asm volatile("s_waitcnt vmcnt(0)" ::: "memory");

    // ---- prologue: B(0),B(1) staged; A(0),A(1) loaded; A(0) written
    GL_B(0, 0, 0); GL_B(0, 1, 1);
    GL_B(1, 2, 0); GL_B(1, 3, 1);
    LD_A(0, 0); LD_A(1, 1);
    WR_A(0, 0);                                // compiler drains through A(0)

    #pragma unroll
    for (int i = 0; i < NMAIN; ++i) {
        asm volatile("s_waitcnt vmcnt(4) lgkmcnt(0)" ::: "memory");
        __builtin_amdgcn_s_barrier();
        __builtin_amdgcn_sched_barrier(0);

        const char* pa = pool + (i % 3) * AB;
        const char* pb = pool + (i % 3) * BBUF;   // +BOFFS via boff
        short8 a0 = *reinterpret_cast<const short8*>(pa + aoff0);
        short8 a1 = *reinterpret_cast<const short8*>(pa + aoff1);
        short8 b00 = *reinterpret_cast<const short8*>(pb + boff0);
        short8 b01 = *reinterpret_cast<const short8*>(pb + boff0 + 256);
        short8 b02 = *reinterpret_cast<const short8*>(pb + boff0 + 512);
        short8 b03 = *reinterpret_cast<const short8*>(pb + boff0 + 768);
        short8 b10 = *reinterpret_cast<const short8*>(pb + boff1);
        short8 b11 = *reinterpret_cast<const short8*>(pb + boff1 + 256);
        short8 b12 = *reinterpret_cast<const short8*>(pb + boff1 + 512);
        short8 b13 = *reinterpret_cast<const short8*>(pb + boff1 + 768);

        const int t0 = (2 * (i + 2)     > 24) ? 24 : 2 * (i + 2);
        const int t1 = (2 * (i + 2) + 1 > 24) ? 24 : 2 * (i + 2) + 1;
        GL_B((i + 2) % 3, t0, 0);
        GL_B((i + 2) % 3, t1, 1);
        LD_A((i + 2) % 3, i + 2);
        WR_A((i + 1) % 3, (i + 1) % 3);

        acc[0] = __builtin_amdgcn_mfma_f32_16x16x32_bf16(a0, b00, acc[0], 0, 0, 0);
        acc[1] = __builtin_amdgcn_mfma_f32_16x16x32_bf16(a0, b01, acc[1], 0, 0, 0);
        acc[2] = __builtin_amdgcn_mfma_f32_16x16x32_bf16(a0, b02, acc[2], 0, 0, 0);
        acc[3] = __builtin_amdgcn_mfma_f32_16x16x32_bf16(a0, b03, acc[3], 0, 0, 0);
        acc[0] = __builtin_amdgcn_mfma_f32_16x16x32_bf16(a1, b10, acc[0], 0, 0, 0);
        acc[1] = __builtin_amdgcn_mfma_f32_16x16x32_bf16(a1, b11, acc[1], 0, 0, 0);
        acc[2] = __builtin_amdgcn_mfma_f32_16x16x32_bf16(a1, b12, acc[2], 0, 0, 0);
        acc[3] = __builtin_amdgcn_mfma_f32_16x16x32_bf16(a1, b13, acc[3], 0, 0, 0);
    }
#undef LD_A
#undef WR_A

    // ---- tail: tile 24 covers k 768..799 (x valid to 783: kc<2 only) ----
    asm volatile("s_waitcnt vmcnt(0) lgkmcnt(0)" ::: "memory");
    __builtin_amdgcn_s_barrier();
    __builtin_amdgcn_sched_barrier(0);

    GL_B(0, 24, 0);
    f32x4 t0v = (f32x4)(0.f), t1v = (f32x4)(0.f);
    {
        int trow = m0 + wr * 16 + r16; if (trow >= B) trow = B - 1;
        const float* xt = x + (size_t)trow * 784;
        if (kc < 2) {
            t0v = *reinterpret_cast<const f32x4*>(xt + 768 + kc * 8);
            t1v = *reinterpret_cast<const f32x4*>(xt + 768 + kc * 8 + 4);
        }
    }
    asm volatile("s_waitcnt vmcnt(0)" ::: "memory");
    __builtin_amdgcn_s_barrier();
    __builtin_amdgcn_sched_barrier(0);
    {
        __hip_bfloat162 p0 = __float22bfloat162_rn(make_float2(t0v[0], t0v[1]));
        __hip_bfloat162 p1 = __float22bfloat162_rn(make_float2(t0v[2], t0v[3]));
        __hip_bfloat162 p2 = __float22bfloat162_rn(make_float2(t1v[0], t1v[1]));
        __hip_bfloat162 p3 = __float22bfloat162_rn(make_float2(t1v[2], t1v[3]));
        short8 af;
        reinterpret_cast<unsigned int*>(&af)[0] = *reinterpret_cast<unsigned int*>(&p0);
        reinterpret_cast<unsigned int*>(&af)[1] = *reinterpret_cast<unsigned int*>(&p1);
        reinterpret_cast<unsigned int*>(&af)[2] = *reinterpret_cast<unsigned int*>(&p2);
        reinterpret_cast<unsigned int*>(&af)[3] = *reinterpret_cast<unsigned int*>(&p3);
        const char* pb = pool;                 // buf 0, kk=0 half
        short8 b0 = *reinterpret_cast<const short8*>(pb + boff0);
        short8 b1 = *reinterpret_cast<const short8*>(pb + boff0 + 256);
        short8 b2 = *reinterpret_cast<const short8*>(pb + boff0 + 512);
        short8 b3 = *reinterpret_cast<const short8*>(pb + boff0 + 768);
        acc[0] = __builtin_amdgcn_mfma_f32_16x16x32_bf16(af, b0, acc[0], 0, 0, 0);
        acc[1] = __builtin_amdgcn_mfma_f32_16x16x32_bf16(af, b1, acc[1], 0, 0, 0);
        acc[2] = __builtin_amdgcn_mfma_f32_16x16x32_bf16(af, b2, acc[2], 0, 0, 0);
        acc[3] = __builtin_amdgcn_mfma_f32_16x16x32_bf16(af, b3, acc[3], 0, 0, 0);
    }
#undef GL_B

    // all LDS reads done before overlaying pool with Hs
    asm volatile("s_waitcnt lgkmcnt(0)" ::: "memory");
    __builtin_amdgcn_s_barrier();
    __builtin_amdgcn_sched_barrier(0);

    // ---- epilogue: bias + ReLU -> Hs (bf16), overlays pool ----
    unsigned short (*Hs)[136] = (unsigned short (*)[136])pool;
    #pragma unroll
    for (int j = 0; j < 4; ++j) {
        int ncol = wc * 64 + j * 16 + r16;
        float bias = fc1_b[ncol];
        #pragma unroll
        for (int r = 0; r < 4; ++r) {
            int mrow = wr * 16 + kc * 4 + r;
            float h = acc[j][r] + bias;
            Hs[mrow][ncol] = f2bf(h > 0.f ? h : 0.f);
        }
    }
    __syncthreads();

    // ---- stage 2: out[64][10] = Hs @ fc2^T + b2 (fc2 bf16 from L1) ----
    #pragma unroll
    for (int it = 0; it < 2; ++it) {
        int idx = it * 512 + tid;              // 0..1023, valid < 640
        if (idx < BM * 10) {
            int row = idx / 10, j = idx - row * 10;
            if ((m0 + row) < B) {
                float sum = fc2_b[j];
                const unsigned short* wrow = fc2wb + j * 128;
                #pragma unroll
                for (int n8 = 0; n8 < 16; ++n8) {
                    short8 h = *reinterpret_cast<const short8*>(&Hs[row][n8 * 8]);
                    short8 w = *reinterpret_cast<const short8*>(wrow + n8 * 8);
                    #pragma unroll
                    for (int k2 = 0; k2 < 8; ++k2)
                        sum += bf2f(((unsigned short*)&h)[k2]) *
                               bf2f(((unsigned short*)&w)[k2]);
                }
                out[(size_t)(m0 + row) * 10 + j] = sum;
            }
        }
    }
}

extern "C" void kernel_launch(void* const* d_in, const int* in_sizes, int n_in,
                              void* d_out, int out_size, void* d_ws, size_t ws_size,
                              hipStream_t stream) {
    const float* x      = (const float*)d_in[0];
    const float* conv_w = (const float*)d_in[1];
    const float* fc1_w  = (const float*)d_in[2];
    const float* fc1_b  = (const float*)d_in[3];
    const float* fc2_w  = (const float*)d_in[4];
    const float* fc2_b  = (const float*)d_in[5];
    float* out = (float*)d_out;
    unsigned short* ws = (unsigned short*)d_ws;   // 103680 bf16 = 207360 B

    int B = in_sizes[0] / 784;

    weff_prep<<<(128 * 800 + 255) / 256, 256, 0, stream>>>(fc1_w, conv_w, fc2_w, ws);

    int nblk = (B + BM - 1) / BM;
    fused_fwd<<<nblk, 512, 0, stream>>>(x, ws, fc1_b, fc2_b, out, B);
}